// Round 5
// baseline (56.395 us; speedup 1.0000x reference)
//
#include <hip/hip_runtime.h>
#include <hip/hip_bf16.h>
#include <cstddef>

#define D_IN 512
#define BLOCK 256
#define RPB 32     // rows per block = 4 waves x 8 rows

typedef float f4 __attribute__((ext_vector_type(4)));

#define NTLOAD(p) __builtin_nontemporal_load(p)

// ---------------------------------------------------------------------------
// Gate helpers (M-build only). Template params keep all state[] indices
// compile-time (registers, never scratch). Wire q = bit (3-q).
// ---------------------------------------------------------------------------
template<int BIT>
__device__ __forceinline__ void applyG(float* sr, float* si,
    float u00r, float u00i, float u01r, float u01i,
    float u10r, float u10i, float u11r, float u11i)
{
#pragma unroll
    for (int m = 0; m < 8; ++m) {
        const int lo = m & (BIT - 1);
        const int i0 = ((m ^ lo) << 1) | lo;
        const int i1 = i0 | BIT;
        float a0r = sr[i0], a0i = si[i0];
        float a1r = sr[i1], a1i = si[i1];
        float n0r = u00r * a0r - u00i * a0i + u01r * a1r - u01i * a1i;
        float n0i = u00r * a0i + u00i * a0r + u01r * a1i + u01i * a1r;
        float n1r = u10r * a0r - u10i * a0i + u11r * a1r - u11i * a1i;
        float n1i = u10r * a0i + u10i * a0r + u11r * a1i + u11i * a1r;
        sr[i0] = n0r; si[i0] = n0i;
        sr[i1] = n1r; si[i1] = n1i;
    }
}

template<int CB, int TB>
__device__ __forceinline__ void applyCNOT(float* sr, float* si)
{
    constexpr int FREE = 15 & ~CB & ~TB;
    constexpr int LO = FREE & (-FREE);
    constexpr int HI = FREE ^ LO;
#pragma unroll
    for (int m = 0; m < 4; ++m) {
        const int idx = CB | ((m & 1) ? LO : 0) | ((m & 2) ? HI : 0);
        const int j = idx | TB;
        float tr = sr[idx]; sr[idx] = sr[j]; sr[j] = tr;
        float ti = si[idx]; si[idx] = si[j]; si[j] = ti;
    }
}

// ---------------------------------------------------------------------------
// Single fused kernel.
//  Phase 0 (wave 0 only): build M (16x16, out = r^T M r) into LDS.
//    amp_embedded = (-i)^pop(idx) * r[idx], r real product of cos/sin(a/2);
//    final = U amp; out = sum_k (1-pop(k)/2)|final_k|^2 = r^T M r with
//    M = sum_k w_k (VR_k VR_k^T + VI_k VI_k^T), V[:,j] = (-i)^pop(j) U e_j.
//    All state arrays use compile-time indices (lane-membership via i==lane).
//  Phase 1 (all waves): R3's GEMM. Lane sub owns k-chunk sub (coalesced
//    512B segments), weights in 16 f4 regs, butterfly allreduce; lane sub==p
//    keeps row (p*2+half)'s 4 dots in registers.
//  Phase 2 (after one barrier): 8 lanes/wave finish rows: tanh, 4 sincos,
//    r^T M r (Mlds reads are same-address broadcasts), coalesced 32B store.
// ---------------------------------------------------------------------------
__global__ __launch_bounds__(BLOCK) void qhead_fused(
    const float* __restrict__ x,
    const float* __restrict__ fc_w,
    const float* __restrict__ fc_b,
    const float* __restrict__ w,
    float* __restrict__ out, int B)
{
    __shared__ float VR[16][16], VI[16][16];
    __shared__ float Mlds[256];

    const int t    = threadIdx.x;
    const int lane = t & 63;
    const int wv   = t >> 6;
    const int sub  = lane & 31;
    const int half = lane >> 5;
    const int row0w = blockIdx.x * RPB + wv * 8;

    // ---- Phase 0: wave 0 builds M ----
    if (wv == 0) {
        float sr[16], si[16];
#pragma unroll
        for (int i = 0; i < 16; ++i) {
            sr[i] = (i == lane) ? 1.f : 0.f;   // basis e_lane (lanes>=16: zero)
            si[i] = 0.f;
        }

#define ROTG(g, q)                                                          \
        {                                                                   \
            float phi = w[(g) * 3 + 0], th = w[(g) * 3 + 1],                \
                  om  = w[(g) * 3 + 2];                                     \
            float sn, cs;  sincosf(th * 0.5f, &sn, &cs);                    \
            float sa, ca;  sincosf((phi + om) * 0.5f, &sa, &ca);            \
            float sd, cd;  sincosf((phi - om) * 0.5f, &sd, &cd);            \
            applyG<(1 << (3 - (q)))>(sr, si,  cs * ca, -cs * sa,            \
                                     -sn * cd, -sn * sd,                    \
                                      sn * cd, -sn * sd,                    \
                                      cs * ca,  cs * sa);                   \
        }
        // Layer 0: Rot on wires 0..3, CNOT ring range 1
        ROTG(0, 0) ROTG(1, 1) ROTG(2, 2) ROTG(3, 3)
        applyCNOT<8, 4>(sr, si);
        applyCNOT<4, 2>(sr, si);
        applyCNOT<2, 1>(sr, si);
        applyCNOT<1, 8>(sr, si);
        // Layer 1: Rot, CNOT ring range 2
        ROTG(4, 0) ROTG(5, 1) ROTG(6, 2) ROTG(7, 3)
        applyCNOT<8, 2>(sr, si);
        applyCNOT<4, 1>(sr, si);
        applyCNOT<2, 8>(sr, si);
        applyCNOT<1, 4>(sr, si);
#undef ROTG

        if (lane < 16) {
            const int pm = __popc(lane) & 3;   // V[:,j] = (-i)^pop(j) U[:,j]
#pragma unroll
            for (int k = 0; k < 16; ++k) {
                float re = sr[k], im = si[k];
                float vr = (pm == 0) ? re : (pm == 1) ? im
                         : (pm == 2) ? -re : -im;
                float vi = (pm == 0) ? im : (pm == 1) ? -re
                         : (pm == 2) ? -im : re;
                VR[k][lane] = vr;  VI[k][lane] = vi;
            }
        }
        // full wave 0: 4 M-entries per lane (in-wave LDS ordering; no barrier)
#pragma unroll
        for (int q = 0; q < 4; ++q) {
            const int e = lane + q * 64;
            const int j = e >> 4, b = e & 15;
            float acc = 0.f;
#pragma unroll
            for (int k = 0; k < 16; ++k) {
                const float wk = 1.0f - 0.5f * (float)__popc(k);
                acc += wk * (VR[k][j] * VR[k][b] + VI[k][j] * VI[k][b]);
            }
            Mlds[e] = acc;
        }
    }

    // ---- Phase 1: GEMM (R3 core) ----
    const f4* w4 = (const f4*)fc_w;
    f4 wreg[4][4];
#pragma unroll
    for (int jj = 0; jj < 4; ++jj)
#pragma unroll
        for (int it = 0; it < 4; ++it)
            wreg[jj][it] = w4[jj * 128 + it * 32 + sub];

    const f4* x4 = (const f4*)x;
    float kd0 = 0.f, kd1 = 0.f, kd2 = 0.f, kd3 = 0.f;

#pragma unroll
    for (int p = 0; p < 4; ++p) {
        int rp = row0w + p * 2 + half;
        if (rp >= B) rp = B - 1;
        const f4* xr = x4 + (size_t)rp * 128 + sub;

        f4 v0 = NTLOAD(xr);
        f4 v1 = NTLOAD(xr + 32);
        f4 v2 = NTLOAD(xr + 64);
        f4 v3 = NTLOAD(xr + 96);

        float s0 = 0.f, s1 = 0.f, s2 = 0.f, s3 = 0.f;
#pragma unroll
        for (int c = 0; c < 4; ++c) {
            f4 v = (c == 0) ? v0 : (c == 1) ? v1 : (c == 2) ? v2 : v3;
            s0 += v[0]*wreg[0][c][0] + v[1]*wreg[0][c][1]
                + v[2]*wreg[0][c][2] + v[3]*wreg[0][c][3];
            s1 += v[0]*wreg[1][c][0] + v[1]*wreg[1][c][1]
                + v[2]*wreg[1][c][2] + v[3]*wreg[1][c][3];
            s2 += v[0]*wreg[2][c][0] + v[1]*wreg[2][c][1]
                + v[2]*wreg[2][c][2] + v[3]*wreg[2][c][3];
            s3 += v[0]*wreg[3][c][0] + v[1]*wreg[3][c][1]
                + v[2]*wreg[3][c][2] + v[3]*wreg[3][c][3];
        }

        // butterfly allreduce within the 32-lane group
#pragma unroll
        for (int off = 1; off < 32; off <<= 1) {
            s0 += __shfl_xor(s0, off);
            s1 += __shfl_xor(s1, off);
            s2 += __shfl_xor(s2, off);
            s3 += __shfl_xor(s3, off);
        }

        if (sub == p) { kd0 = s0; kd1 = s1; kd2 = s2; kd3 = s3; }
    }

    __syncthreads();   // Mlds ready (wave 0) before any lane's sim

    // ---- Phase 2: sim for the 8 keeper lanes per wave ----
    if (sub < 4) {
        const int row = row0w + sub * 2 + half;

        float c0, c1, c2, c3, s0, s1, s2, s3;
        sincosf(tanhf(kd0 + fc_b[0]) * 0.5f, &s0, &c0);
        sincosf(tanhf(kd1 + fc_b[1]) * 0.5f, &s1, &c1);
        sincosf(tanhf(kd2 + fc_b[2]) * 0.5f, &s2, &c2);
        sincosf(tanhf(kd3 + fc_b[3]) * 0.5f, &s3, &c3);

        // r[idx]: bit3 = wire0 ... bit0 = wire3
        float rA[4] = { c0*c1, c0*s1, s0*c1, s0*s1 };
        float rB[4] = { c2*c3, c2*s3, s2*c3, s2*s3 };
        float r[16];
#pragma unroll
        for (int u = 0; u < 4; ++u)
#pragma unroll
            for (int v = 0; v < 4; ++v)
                r[u * 4 + v] = rA[u] * rB[v];

        const f4* M4 = (const f4*)Mlds;
        float res = 0.f;
#pragma unroll
        for (int a = 0; a < 16; ++a) {
            float ta = 0.f;
#pragma unroll
            for (int bq = 0; bq < 4; ++bq) {
                f4 m = M4[a * 4 + bq];
                ta += m[0] * r[bq * 4 + 0] + m[1] * r[bq * 4 + 1]
                    + m[2] * r[bq * 4 + 2] + m[3] * r[bq * 4 + 3];
            }
            res += ta * r[a];
        }
        if (row < B) out[row] = res;
    }
}

extern "C" void kernel_launch(void* const* d_in, const int* in_sizes, int n_in,
                              void* d_out, int out_size, void* d_ws, size_t ws_size,
                              hipStream_t stream)
{
    const float* x    = (const float*)d_in[0];
    const float* fc_w = (const float*)d_in[1];
    const float* fc_b = (const float*)d_in[2];
    const float* w    = (const float*)d_in[3];
    float* out = (float*)d_out;

    const int B = in_sizes[0] / D_IN;

    qhead_fused<<<(B + RPB - 1) / RPB, BLOCK, 0, stream>>>(
        x, fc_w, fc_b, w, out, B);
}

// Round 6
// 39.679 us; speedup vs baseline: 1.4213x; 1.4213x over previous
//
#include <hip/hip_runtime.h>
#include <hip/hip_bf16.h>
#include <cstddef>

#define D_IN 512
#define BLOCK 256
#define RPB 32     // rows per block = 4 waves x 8 rows

typedef float f4 __attribute__((ext_vector_type(4)));

// ---------------------------------------------------------------------------
// Gate helpers (pre-kernel only). Template params keep all state[] indices
// compile-time (registers, never scratch). Wire q = bit (3-q).
// ---------------------------------------------------------------------------
template<int BIT>
__device__ __forceinline__ void applyG(float* sr, float* si,
    float u00r, float u00i, float u01r, float u01i,
    float u10r, float u10i, float u11r, float u11i)
{
#pragma unroll
    for (int m = 0; m < 8; ++m) {
        const int lo = m & (BIT - 1);
        const int i0 = ((m ^ lo) << 1) | lo;
        const int i1 = i0 | BIT;
        float a0r = sr[i0], a0i = si[i0];
        float a1r = sr[i1], a1i = si[i1];
        float n0r = u00r * a0r - u00i * a0i + u01r * a1r - u01i * a1i;
        float n0i = u00r * a0i + u00i * a0r + u01r * a1i + u01i * a1r;
        float n1r = u10r * a0r - u10i * a0i + u11r * a1r - u11i * a1i;
        float n1i = u10r * a0i + u10i * a0r + u11r * a1i + u11i * a1r;
        sr[i0] = n0r; si[i0] = n0i;
        sr[i1] = n1r; si[i1] = n1i;
    }
}

template<int CB, int TB>
__device__ __forceinline__ void applyCNOT(float* sr, float* si)
{
    constexpr int FREE = 15 & ~CB & ~TB;
    constexpr int LO = FREE & (-FREE);
    constexpr int HI = FREE ^ LO;
#pragma unroll
    for (int m = 0; m < 4; ++m) {
        const int idx = CB | ((m & 1) ? LO : 0) | ((m & 2) ? HI : 0);
        const int j = idx | TB;
        float tr = sr[idx]; sr[idx] = sr[j]; sr[j] = tr;
        float ti = si[idx]; si[idx] = si[j]; si[j] = ti;
    }
}

// ---------------------------------------------------------------------------
// Pre-kernel (1 wave): build M (16x16 real symmetric) with out = r^T M r,
// r[idx] = prod_q (bit_q(idx) ? sin(a_q/2) : cos(a_q/2)).
// amp_embedded = (-i)^pop(idx) r[idx]; final = U amp = V r,
// V[:,j] = (-i)^pop(j) U e_j; M = sum_k (1-pop(k)/2)(VR_k VR_k^T + VI_k VI_k^T).
// Lane j<16 builds U e_j with compile-time state indices (i==lane selects).
// Register-only: NO runtime-indexed arrays (R4's scratch-spill lesson).
// ---------------------------------------------------------------------------
__global__ void qhead_pre(const float* __restrict__ w, float* __restrict__ M)
{
    __shared__ float VR[16][16], VI[16][16];
    const int lane = threadIdx.x & 63;

    float sr[16], si[16];
#pragma unroll
    for (int i = 0; i < 16; ++i) {
        sr[i] = (i == lane) ? 1.f : 0.f;   // basis e_lane (lanes>=16 all zero)
        si[i] = 0.f;
    }

#define ROTG(g, q)                                                          \
    {                                                                       \
        float phi = w[(g) * 3 + 0], th = w[(g) * 3 + 1],                    \
              om  = w[(g) * 3 + 2];                                         \
        float sn, cs;  sincosf(th * 0.5f, &sn, &cs);                        \
        float sa, ca;  sincosf((phi + om) * 0.5f, &sa, &ca);                \
        float sd, cd;  sincosf((phi - om) * 0.5f, &sd, &cd);                \
        applyG<(1 << (3 - (q)))>(sr, si,  cs * ca, -cs * sa,                \
                                 -sn * cd, -sn * sd,                        \
                                  sn * cd, -sn * sd,                        \
                                  cs * ca,  cs * sa);                       \
    }
    // Layer 0: Rot wires 0..3, CNOT ring range 1
    ROTG(0, 0) ROTG(1, 1) ROTG(2, 2) ROTG(3, 3)
    applyCNOT<8, 4>(sr, si);
    applyCNOT<4, 2>(sr, si);
    applyCNOT<2, 1>(sr, si);
    applyCNOT<1, 8>(sr, si);
    // Layer 1: Rot, CNOT ring range 2
    ROTG(4, 0) ROTG(5, 1) ROTG(6, 2) ROTG(7, 3)
    applyCNOT<8, 2>(sr, si);
    applyCNOT<4, 1>(sr, si);
    applyCNOT<2, 8>(sr, si);
    applyCNOT<1, 4>(sr, si);
#undef ROTG

    if (lane < 16) {
        const int pm = __popc(lane) & 3;   // V[:,j] = (-i)^pop(j) U[:,j]
#pragma unroll
        for (int k = 0; k < 16; ++k) {
            float re = sr[k], im = si[k];
            float vr = (pm == 0) ? re : (pm == 1) ? im
                     : (pm == 2) ? -re : -im;
            float vi = (pm == 0) ? im : (pm == 1) ? -re
                     : (pm == 2) ? -im : re;
            VR[k][lane] = vr;  VI[k][lane] = vi;
        }
    }
    // single wave: LDS write->read ordering within the wave is compiler-waited
#pragma unroll
    for (int q = 0; q < 4; ++q) {
        const int e = lane + q * 64;
        const int j = e >> 4, b = e & 15;
        float acc = 0.f;
#pragma unroll
        for (int k = 0; k < 16; ++k) {
            const float wk = 1.0f - 0.5f * (float)__popc(k);
            acc += wk * (VR[k][j] * VR[k][b] + VI[k][j] * VI[k][b]);
        }
        M[e] = acc;
    }
}

// ---------------------------------------------------------------------------
// Main kernel: R3's proven GEMM core + barrier-free fused sim tail.
// Wave handles 8 rows in 4 passes of 2 (lanes: sub = k-chunk, half = row of
// pair). Loads: 512B contiguous per 32-lane group (coalesced), weights in 16
// f4 regs, 2-deep software pipeline. Butterfly allreduce per pass; lane
// sub==p keeps row (p*2+half)'s 4 dots. Tail: 8 keeper lanes/wave do
// tanh + sincos + r^T M r (M from global, 1KB, L1-hot) and store.
// No LDS, no __syncthreads.
// ---------------------------------------------------------------------------
__global__ __launch_bounds__(BLOCK) void qhead_main(
    const float* __restrict__ x,
    const float* __restrict__ fc_w,
    const float* __restrict__ fc_b,
    const float* __restrict__ Mg,
    float* __restrict__ out, int B)
{
    const int t    = threadIdx.x;
    const int lane = t & 63;
    const int wv   = t >> 6;
    const int sub  = lane & 31;
    const int half = lane >> 5;
    const int row0w = blockIdx.x * RPB + wv * 8;

    // weights: 16 f4 regs per lane (row j, chunk it*32+sub)
    const f4* w4 = (const f4*)fc_w;
    f4 wreg[4][4];
#pragma unroll
    for (int jj = 0; jj < 4; ++jj)
#pragma unroll
        for (int it = 0; it < 4; ++it)
            wreg[jj][it] = w4[jj * 128 + it * 32 + sub];

    int rp0 = row0w + 0 + half; if (rp0 >= B) rp0 = B - 1;
    int rp1 = row0w + 2 + half; if (rp1 >= B) rp1 = B - 1;
    int rp2 = row0w + 4 + half; if (rp2 >= B) rp2 = B - 1;
    int rp3 = row0w + 6 + half; if (rp3 >= B) rp3 = B - 1;
    const f4* x4 = (const f4*)x;

    float kd0 = 0.f, kd1 = 0.f, kd2 = 0.f, kd3 = 0.f;

#define LOADX(dst, r)                                                       \
    {                                                                       \
        const f4* xr = x4 + (size_t)(r) * 128 + sub;                        \
        dst[0] = xr[0]; dst[1] = xr[32]; dst[2] = xr[64]; dst[3] = xr[96];  \
    }
#define PASS(p, xv)                                                         \
    {                                                                       \
        float s0 = 0.f, s1 = 0.f, s2 = 0.f, s3 = 0.f;                       \
        _Pragma("unroll")                                                   \
        for (int c = 0; c < 4; ++c) {                                       \
            f4 v = xv[c];                                                   \
            s0 += v[0]*wreg[0][c][0] + v[1]*wreg[0][c][1]                   \
                + v[2]*wreg[0][c][2] + v[3]*wreg[0][c][3];                  \
            s1 += v[0]*wreg[1][c][0] + v[1]*wreg[1][c][1]                   \
                + v[2]*wreg[1][c][2] + v[3]*wreg[1][c][3];                  \
            s2 += v[0]*wreg[2][c][0] + v[1]*wreg[2][c][1]                   \
                + v[2]*wreg[2][c][2] + v[3]*wreg[2][c][3];                  \
            s3 += v[0]*wreg[3][c][0] + v[1]*wreg[3][c][1]                   \
                + v[2]*wreg[3][c][2] + v[3]*wreg[3][c][3];                  \
        }                                                                   \
        _Pragma("unroll")                                                   \
        for (int off = 1; off < 32; off <<= 1) {                            \
            s0 += __shfl_xor(s0, off);                                      \
            s1 += __shfl_xor(s1, off);                                      \
            s2 += __shfl_xor(s2, off);                                      \
            s3 += __shfl_xor(s3, off);                                      \
        }                                                                   \
        if (sub == (p)) { kd0 = s0; kd1 = s1; kd2 = s2; kd3 = s3; }         \
    }

    f4 xvA[4], xvB[4];
    LOADX(xvA, rp0);
    LOADX(xvB, rp1);
    PASS(0, xvA);
    LOADX(xvA, rp2);
    PASS(1, xvB);
    LOADX(xvB, rp3);
    PASS(2, xvA);
    PASS(3, xvB);
#undef LOADX
#undef PASS

    // ---- fused tail: 8 keeper lanes per wave ----
    if (sub < 4) {
        const int row = row0w + sub * 2 + half;

        float c0, c1, c2, c3, s0, s1, s2, s3;
        sincosf(tanhf(kd0 + fc_b[0]) * 0.5f, &s0, &c0);
        sincosf(tanhf(kd1 + fc_b[1]) * 0.5f, &s1, &c1);
        sincosf(tanhf(kd2 + fc_b[2]) * 0.5f, &s2, &c2);
        sincosf(tanhf(kd3 + fc_b[3]) * 0.5f, &s3, &c3);

        // r[idx]: bit3 = wire0 ... bit0 = wire3
        float rA[4] = { c0*c1, c0*s1, s0*c1, s0*s1 };
        float rB[4] = { c2*c3, c2*s3, s2*c3, s2*s3 };
        float r[16];
#pragma unroll
        for (int u = 0; u < 4; ++u)
#pragma unroll
            for (int v = 0; v < 4; ++v)
                r[u * 4 + v] = rA[u] * rB[v];

        const f4* M4 = (const f4*)Mg;
        float res = 0.f;
#pragma unroll
        for (int a = 0; a < 16; ++a) {
            float ta = 0.f;
#pragma unroll
            for (int bq = 0; bq < 4; ++bq) {
                f4 m = M4[a * 4 + bq];
                ta += m[0] * r[bq * 4 + 0] + m[1] * r[bq * 4 + 1]
                    + m[2] * r[bq * 4 + 2] + m[3] * r[bq * 4 + 3];
            }
            res += ta * r[a];
        }
        if (row < B) out[row] = res;
    }
}

extern "C" void kernel_launch(void* const* d_in, const int* in_sizes, int n_in,
                              void* d_out, int out_size, void* d_ws, size_t ws_size,
                              hipStream_t stream)
{
    const float* x    = (const float*)d_in[0];
    const float* fc_w = (const float*)d_in[1];
    const float* fc_b = (const float*)d_in[2];
    const float* w    = (const float*)d_in[3];
    float* out = (float*)d_out;
    float* M   = (float*)d_ws;           // 256 floats

    const int B = in_sizes[0] / D_IN;

    qhead_pre<<<1, 64, 0, stream>>>(w, M);
    qhead_main<<<(B + RPB - 1) / RPB, BLOCK, 0, stream>>>(
        x, fc_w, fc_b, M, out, B);
}